// Round 15
// baseline (736.970 us; speedup 1.0000x reference)
//
#include <hip/hip_runtime.h>
#include <hip/hip_bf16.h>
#include <cstdint>
#include <cstddef>

#define NN 25000
#define NE 400000
#define NFD 30
#define EFD 10
#define H 40
#define T 5
#define FO 8
#define LAYERS 2
#define TF 200          // T*F
#define PSTR 52         // padded row stride for P1/P2
#define REC 12          // floats per CSR edge record [ea0..9, src, eid]
#define WCN 416         // Wcat rows: A j 0..199 | pad | B j 208..407 | pad
#define WCK 64          // Wcat K (40 real + 24 zero-pad)
#define SHP 72          // LDS bf16 row stride for h tile
#define NBLK (NN / 4)   // k_agg grid
#define SUPB ((NBLK + 63) / 64)   // 98 compact-partial superblocks
#define EPSV 1e-5f

typedef __attribute__((ext_vector_type(8))) short bf16x8;
typedef __attribute__((ext_vector_type(4))) float f32x4;

__device__ inline short bfbits(float v) {
    __hip_bfloat16 b = __float2bfloat16(v);
    return *(short*)&b;
}

// ---------- fused front: prep1(both layers) || degree histogram || h0 matmul ----------
__global__ __launch_bounds__(256) void k_front(const float* __restrict__ enc_w, const float* __restrict__ enc_b,
                                               const float* __restrict__ edge_w, const float* __restrict__ edge_b,
                                               const float* __restrict__ pre_w, const float* __restrict__ pre_b,
                                               const float* __restrict__ post_w,
                                               const float* __restrict__ w1, const float* __restrict__ b1,
                                               float* __restrict__ W3e, float* __restrict__ dvecF,
                                               __hip_bfloat16* __restrict__ Wcat,
                                               __hip_bfloat16* __restrict__ Wp4b, float* __restrict__ Wxd,
                                               float* __restrict__ W1e, float* __restrict__ b1e,
                                               const int* __restrict__ dst, int* __restrict__ cnt,
                                               const float* __restrict__ x, const float* __restrict__ node_w,
                                               const float* __restrict__ node_b, float* __restrict__ h,
                                               int grid1, int gdeg) {
    int blk = blockIdx.x;
    int tid = threadIdx.x;
    if (blk < 2 * grid1) {
        // ----- prep1, both layers -----
        int layer = (blk >= grid1) ? 1 : 0;
        int id = (blk - layer * grid1) * 256 + tid;
        W3e   += (size_t)layer * EFD * TF;
        dvecF += (size_t)layer * TF;
        Wcat  += (size_t)layer * WCN * WCK;
        Wp4b  += (size_t)layer * 40 * 512;
        Wxd   += (size_t)layer * H * H;
        const int B0 = EFD * TF;            // 2000
        const int B1 = B0 + WCN * WCK;      // 28624
        const int B2 = B1 + EFD * 50;       // 29124
        const int B3 = B2 + 40 * 512;       // 49604  (Wp4b[fs4][op 0..127][4], bf16)
        const int B4 = B3 + H * H;          // 51204  (Wxd: 40j x 40f)
        if (id < B0) {
            int m = id / TF, j = id - m * TF;
            int t = j / H, f = j - t * H;
            const float* ew = enc_w + (size_t)layer * H * H;
            const float* pw = pre_w + (size_t)(layer * T + t) * 120 * H;
            float acc = 0.0f;
            for (int k = 0; k < H; k++) {
                float wk = edge_w[m * H + k];
                float g = 0.0f;
                #pragma unroll
                for (int o = 0; o < H; o++) g += ew[k * H + o] * pw[(80 + o) * H + f];
                acc += wk * g;
            }
            W3e[m * TF + j] = acc;
            if (m == 0) {
                const float* eb = enc_b + (size_t)layer * H;
                float dacc = pre_b[(size_t)(layer * T + t) * H + f];
                for (int o = 0; o < H; o++) {
                    float ebe = eb[o];
                    #pragma unroll
                    for (int k = 0; k < H; k++) ebe += edge_b[k] * ew[k * H + o];
                    dacc += ebe * pw[(80 + o) * H + f];
                }
                dvecF[j] = dacc;
            }
        } else if (id < B1) {
            int id2 = id - B0;
            int j = id2 / WCK, k = id2 - j * WCK;
            float val = 0.0f;
            if (k < H) {
                if (j < TF) {                      // A weights: p1 part, pre_w[t][k][f]
                    int t = j / H, f = j - t * H;
                    val = pre_w[((size_t)(layer * T + t) * 120 + k) * H + f];
                } else if (j >= 208 && j < 208 + TF) {   // B weights: p2 part, pre_w[t][40+k][f]
                    int j2 = j - 208;
                    int t = j2 / H, f = j2 - t * H;
                    val = pre_w[((size_t)(layer * T + t) * 120 + H + k) * H + f];
                }
            }
            Wcat[id2] = __float2bfloat16(val);
        } else if (id < B2) {
            if (layer == 0) {
                int id2 = id - B1;
                int m = id2 / 50, o = id2 - m * 50;
                float acc = 0.0f;
                #pragma unroll
                for (int k = 0; k < H; k++) acc += edge_w[m * H + k] * w1[(80 + k) * 50 + o];
                W1e[m * 50 + o] = acc;
                if (m == 0) {
                    float bacc = b1[o];
                    #pragma unroll
                    for (int k = 0; k < H; k++) bacc += edge_b[k] * w1[(80 + k) * 50 + o];
                    b1e[o] = bacc;
                }
            }
        } else if (id < B3) {
            // Wp4b[fs4*512 + col*4 + c]; fs = fs4*4+c in [0,160); col = t*24+grp*8+o (<120)
            int i2 = id - B2;
            int fs4 = i2 >> 9;
            int rem = i2 & 511;
            int col = rem >> 2, c = rem & 3;
            int fs = fs4 * 4 + c;
            float v = 0.0f;
            if (col < 120) {
                int t = col / 24, r2 = col - t * 24;
                int grp = r2 >> 3, o = r2 & 7;
                v = post_w[((size_t)(layer * T + t) * 520 + 40 + grp * 160 + fs) * FO + o];
            }
            Wp4b[i2] = __float2bfloat16(v);
        } else if (id < B4) {
            // Wxd[j*40 + f] = post_w[t][f][o], j = t*8+o
            int i2 = id - B3;
            int j = i2 / H, f = i2 - j * H;
            int t = j >> 3, o = j & 7;
            Wxd[i2] = post_w[((size_t)(layer * T + t) * 520 + f) * FO + o];
        }
    } else if (blk < 2 * grid1 + gdeg) {
        // ----- degree histogram -----
        int e = (blk - 2 * grid1) * 256 + tid;
        if (e < NE) atomicAdd(&cnt[dst[e]], 1);
    } else {
        // ----- h0 = x @ node_w + node_b -----
        int id = (blk - 2 * grid1 - gdeg) * 256 + tid;
        if (id >= NN * H) return;
        int n = id / H, j = id - n * H;
        const float* xr = x + (size_t)n * NFD;
        float acc = node_b[j];
        #pragma unroll
        for (int m = 0; m < NFD; m++) acc += xr[m] * node_w[m * H + j];
        h[id] = acc;
    }
}

// ---------- exclusive scan of cnt -> offsets (shfl-based) + avglog + amp/att ----------
__global__ __launch_bounds__(1024) void k_scan(const int* __restrict__ cnt, int* __restrict__ offs,
                                               float* __restrict__ amp, float* __restrict__ att) {
    __shared__ int wsum[16];
    __shared__ float fsum[16];
    __shared__ float favg;
    int tid = threadIdx.x;
    int lane = tid & 63, wv = tid >> 6;
    // --- log-sum for avg (k_avglog folded in) ---
    {
        float s = 0.0f;
        for (int i = tid; i < NN; i += 1024) s += logf((float)cnt[i] + 1.0f);
        #pragma unroll
        for (int o = 32; o > 0; o >>= 1) s += __shfl_down(s, o);
        if (lane == 0) fsum[wv] = s;
        __syncthreads();
        if (tid == 0) {
            float a = 0.0f;
            #pragma unroll
            for (int i = 0; i < 16; i++) a += fsum[i];
            favg = a / (float)NN;
        }
        __syncthreads();
    }
    float avg = favg;
    int runbase = 0;
    for (int base = 0; base < NN; base += 4096) {
        int i0 = base + tid * 4;
        int4 v = make_int4(0, 0, 0, 0);
        if (i0 < NN) v = *(const int4*)(cnt + i0);   // NN % 4 == 0
        if (i0 < NN) {
            #pragma unroll
            for (int c = 0; c < 4; c++) {
                int cv = (&v.x)[c];
                float c1 = fmaxf((float)cv, 1.0f);
                float lg = logf(c1 + 1.0f);
                amp[i0 + c] = lg / avg;
                att[i0 + c] = avg / lg;
            }
        }
        int tsum = v.x + v.y + v.z + v.w;
        int x = tsum;
        #pragma unroll
        for (int o = 1; o < 64; o <<= 1) {
            int y = __shfl_up(x, o);
            if (lane >= o) x += y;
        }
        if (lane == 63) wsum[wv] = x;
        __syncthreads();
        if (wv == 0 && lane < 16) {
            int wsv = wsum[lane];
            #pragma unroll
            for (int o = 1; o < 16; o <<= 1) {
                int y = __shfl_up(wsv, o);
                if (lane >= o) wsv += y;
            }
            wsum[lane] = wsv;
        }
        __syncthreads();
        int wpref = (wv > 0) ? wsum[wv - 1] : 0;
        int excl = runbase + wpref + x - tsum;
        if (i0 < NN) {
            offs[i0]     = excl;
            offs[i0 + 1] = excl + v.x;
            offs[i0 + 2] = excl + v.x + v.y;
            offs[i0 + 3] = excl + v.x + v.y + v.z;
        }
        runbase += wsum[15];
        __syncthreads();
    }
    if (tid == 0) offs[NN] = runbase;
}

// ---------- fused mid: edge scatter || MFMA A/B for layer 0 (independent workloads) ----------
__global__ __launch_bounds__(256) void k_mid(const int* __restrict__ src, const int* __restrict__ dst,
                                             const float* __restrict__ edge_attr,
                                             const int* __restrict__ offs, int* __restrict__ fill,
                                             float* __restrict__ ea_csr, int* __restrict__ pdst,
                                             const float* __restrict__ h,
                                             const __hip_bfloat16* __restrict__ Wcat,
                                             float* __restrict__ A, __hip_bfloat16* __restrict__ Bbf,
                                             int gab) {
    __shared__ short sh[64 * SHP];           // bf16 bits, zero-padded K (abm path only)
    int blk = blockIdx.x;
    int tid = threadIdx.x;
    if (blk < gab) {
        // ----- abm L0: [64 nodes x 40] @ Wcat -> A fp32, Bbf bf16 -----
        int n0 = blk * 64;
        int nodes = NN - n0; if (nodes > 64) nodes = 64;
        for (int i = tid; i < 64 * SHP; i += 256) sh[i] = 0;
        __syncthreads();
        for (int i = tid; i < nodes * H; i += 256) {
            int f = i % H;
            sh[(i / H) * SHP + f] = bfbits(h[(size_t)n0 * H + i]);
        }
        __syncthreads();

        int wv = tid >> 6, lane = tid & 63;
        int q = lane >> 4, c16 = lane & 15;
        const short* arow = sh + (wv * 16 + c16) * SHP + q * 8;
        bf16x8 a0 = *(const bf16x8*)(arow);       // chunk 0: K 0..31
        bf16x8 a1 = *(const bf16x8*)(arow + 32);  // chunk 1: K 32..63 (zeros beyond 40)
        int gm = n0 + wv * 16 + q * 4;            // D rows: gm..gm+3

        for (int jt = 0; jt < 26; jt++) {
            int col = jt * 16 + c16;
            const short* wrow = (const short*)Wcat + (size_t)col * WCK + q * 8;
            bf16x8 b0 = *(const bf16x8*)(wrow);
            bf16x8 b1 = *(const bf16x8*)(wrow + 32);
            f32x4 acc = {0.0f, 0.0f, 0.0f, 0.0f};
            acc = __builtin_amdgcn_mfma_f32_16x16x32_bf16(a0, b0, acc, 0, 0, 0);
            acc = __builtin_amdgcn_mfma_f32_16x16x32_bf16(a1, b1, acc, 0, 0, 0);
            if (col < TF) {
                #pragma unroll
                for (int r = 0; r < 4; r++) {
                    int row = gm + r;
                    if (row < NN) A[(size_t)row * TF + col] = acc[r];
                }
            } else if (col >= 208) {
                int c2 = col - 208;
                if (c2 < TF) {
                    #pragma unroll
                    for (int r = 0; r < 4; r++) {
                        int row = gm + r;
                        if (row < NN) Bbf[(size_t)row * TF + c2] = __float2bfloat16(acc[r]);
                    }
                }
            }
        }
    } else {
        // ----- scatter edges into CSR records [ea0..9, src, eid] + pdst -----
        int e = (blk - gab) * 256 + tid;
        if (e >= NE) return;
        int d = dst[e];
        int p = offs[d] + atomicAdd(&fill[d], 1);
        const float2* ear = (const float2*)(edge_attr + (size_t)e * EFD);
        float2 v0 = ear[0], v1 = ear[1], v2 = ear[2], v3 = ear[3], v4 = ear[4];
        float4* o = (float4*)(ea_csr + (size_t)p * REC);
        o[0] = make_float4(v0.x, v0.y, v1.x, v1.y);
        o[1] = make_float4(v2.x, v2.y, v3.x, v3.y);
        o[2] = make_float4(v4.x, v4.y, __int_as_float(src[e]), __int_as_float(e));
        pdst[p] = d;
    }
}

// ---------- MFMA A/B with fused BN+residual (layer 1); reduces compact L0 partials in prologue ----------
__global__ __launch_bounds__(256) void k_abm(float* h, const float* __restrict__ cbuf,
                                             const float* __restrict__ partials2,
                                             const float* __restrict__ bng, const float* __restrict__ bnb,
                                             const __hip_bfloat16* __restrict__ Wcat,
                                             float* __restrict__ A, __hip_bfloat16* __restrict__ Bbf) {
    __shared__ short sh[64 * SHP];           // bf16 bits, zero-padded K
    __shared__ float bns[80];                // [sum(40) | sumsq(40)]
    int tid = threadIdx.x;
    int n0 = blockIdx.x * 64;
    int nodes = NN - n0; if (nodes > 64) nodes = 64;
    if (tid < 80) {
        float s = 0.0f;
        for (int i = 0; i < SUPB; i++) s += partials2[i * 80 + tid];
        bns[tid] = s;
    }
    for (int i = tid; i < 64 * SHP; i += 256) sh[i] = 0;
    __syncthreads();
    float invN = 1.0f / (float)NN;
    for (int i = tid; i < nodes * H; i += 256) {
        int f = i % H;
        float hv = h[(size_t)n0 * H + i];
        float mu = bns[f] * invN;
        float var = bns[40 + f] * invN - mu * mu;
        float c = (cbuf[(size_t)n0 * H + i] - mu) * rsqrtf(var + EPSV) * bng[f] + bnb[f];
        float hn = (hv + fmaxf(c, 0.0f)) * 0.5f;
        h[(size_t)n0 * H + i] = hn;          // materialize h' for k_agg combine
        sh[(i / H) * SHP + f] = bfbits(hn);
    }
    __syncthreads();

    int wv = tid >> 6, lane = tid & 63;
    int q = lane >> 4, c16 = lane & 15;
    const short* arow = sh + (wv * 16 + c16) * SHP + q * 8;
    bf16x8 a0 = *(const bf16x8*)(arow);       // chunk 0: K 0..31
    bf16x8 a1 = *(const bf16x8*)(arow + 32);  // chunk 1: K 32..63 (zeros beyond 40)
    int gm = n0 + wv * 16 + q * 4;            // D rows: gm..gm+3

    for (int jt = 0; jt < 26; jt++) {
        int col = jt * 16 + c16;
        const short* wrow = (const short*)Wcat + (size_t)col * WCK + q * 8;
        bf16x8 b0 = *(const bf16x8*)(wrow);
        bf16x8 b1 = *(const bf16x8*)(wrow + 32);
        f32x4 acc = {0.0f, 0.0f, 0.0f, 0.0f};
        acc = __builtin_amdgcn_mfma_f32_16x16x32_bf16(a0, b0, acc, 0, 0, 0);
        acc = __builtin_amdgcn_mfma_f32_16x16x32_bf16(a1, b1, acc, 0, 0, 0);
        if (col < TF) {                       // A region
            #pragma unroll
            for (int r = 0; r < 4; r++) {
                int row = gm + r;
                if (row < NN) A[(size_t)row * TF + col] = acc[r];
            }
        } else if (col >= 208) {
            int c2 = col - 208;
            if (c2 < TF) {                    // B region
                #pragma unroll
                for (int r = 0; r < 4; r++) {
                    int row = gm + r;
                    if (row < NN) Bbf[(size_t)row * TF + c2] = __float2bfloat16(acc[r]);
                }
            }
        }
    }
}

// ---------- aggregation (wave-PAIR per node) + post-projection + lin + compact BN-partials ----------
__global__ __launch_bounds__(512) void k_agg(const float* __restrict__ ea_csr,
                                             const __hip_bfloat16* __restrict__ Bbf,
                                             const float* __restrict__ A, const float* __restrict__ w3e,
                                             const float* __restrict__ dvecF, const int* __restrict__ cnt,
                                             const int* __restrict__ offs,
                                             const float* __restrict__ h,
                                             const __hip_bfloat16* __restrict__ Wp4b, const float* __restrict__ Wxd,
                                             const float* __restrict__ pbL,
                                             const float* __restrict__ amp, const float* __restrict__ att,
                                             const float* __restrict__ lwL, const float* __restrict__ lbL,
                                             float* __restrict__ cbuf, float* __restrict__ partials2) {
    __shared__ float sst[4 * 800];           // per-node stats node-major; aliased after proj:
    __shared__ float shh[4 * H];             //   spart [0,960) | scp [1024,1184) | lred [1280,1440)
    __shared__ float mrg[4 * 16 * 52];       // sub-wave partial merge [node][16][lane(50)+pad]
    float* spart = sst;
    float* scp   = sst + 1024;
    float* lred  = sst + 1280;
    int tid = threadIdx.x;
    int lane = tid & 63;
    int wv = tid >> 6;                       // 8 waves
    int nd = wv >> 1;                        // node slot 0..3
    int sub = wv & 1;                        // half of the edge list
    int n0 = blockIdx.x * 4;                 // NN % 4 == 0
    // SGPR node index -> scalar (SMEM) loads for deg/start/records (r4 post-mortem: critical)
    int n = __builtin_amdgcn_readfirstlane(n0 + nd);
    if (tid < 4 * H) shh[tid] = h[(size_t)n0 * H + tid];
    int deg = cnt[n];
    int start = offs[n];
    bool comp = lane < TF / 4; // lanes 0..49
    float4 w3q[EFD];
    float4 dj4 = make_float4(0, 0, 0, 0), a4 = make_float4(0, 0, 0, 0);
    if (comp) {
        #pragma unroll
        for (int m = 0; m < EFD; m++) w3q[m] = *(const float4*)(w3e + m * TF + 4 * lane);
        dj4 = *(const float4*)(dvecF + 4 * lane);
        a4  = *(const float4*)(A + (size_t)n * TF + 4 * lane);
    }
    float sx = 0, sy = 0, sz = 0, sw_ = 0;
    float qx = 0, qy = 0, qz = 0, qw = 0;
    float mnx = 3.4e38f, mny = 3.4e38f, mnz = 3.4e38f, mnw = 3.4e38f;
    float mxx = -3.4e38f, mxy = -3.4e38f, mxz = -3.4e38f, mxw = -3.4e38f;
    const float4* recb = (const float4*)ea_csr + (size_t)start * 3;
    const uint16_t* Bu = (const uint16_t*)Bbf;

    auto edge = [&](float4 qa, float4 qb, float4 qc, uint2 bv) {
        float b0 = __uint_as_float(bv.x << 16);
        float b1 = __uint_as_float(bv.x & 0xffff0000u);
        float b2 = __uint_as_float(bv.y << 16);
        float b3 = __uint_as_float(bv.y & 0xffff0000u);
        float eav[EFD] = {qa.x, qa.y, qa.z, qa.w, qb.x, qb.y, qb.z, qb.w, qc.x, qc.y};
        float cx = dj4.x, cy = dj4.y, cz = dj4.z, cw = dj4.w;
        #pragma unroll
        for (int m = 0; m < EFD; m++) {
            cx = fmaf(eav[m], w3q[m].x, cx);
            cy = fmaf(eav[m], w3q[m].y, cy);
            cz = fmaf(eav[m], w3q[m].z, cz);
            cw = fmaf(eav[m], w3q[m].w, cw);
        }
        float ux = b0 + cx, uy = b1 + cy, uz = b2 + cz, uw = b3 + cw;
        sx += ux; qx = fmaf(ux, ux, qx); mnx = fminf(mnx, ux); mxx = fmaxf(mxx, ux);
        sy += uy; qy = fmaf(uy, uy, qy); mny = fminf(mny, uy); mxy = fmaxf(mxy, uy);
        sz += uz; qz = fmaf(uz, uz, qz); mnz = fminf(mnz, uz); mxz = fmaxf(mxz, uz);
        sw_ += uw; qw = fmaf(uw, uw, qw); mnw = fminf(mnw, uw); mxw = fmaxf(mxw, uw);
    };

    // ---- edge loop: sub-wave 0 takes chunks 0,8,16,..; sub-wave 1 takes 4,12,20,.. ----
    int r = sub * 4;
    for (; r + 4 <= deg; r += 8) {
        float4 qa0 = recb[(r + 0) * 3], qb0 = recb[(r + 0) * 3 + 1], qc0 = recb[(r + 0) * 3 + 2];
        float4 qa1 = recb[(r + 1) * 3], qb1 = recb[(r + 1) * 3 + 1], qc1 = recb[(r + 1) * 3 + 2];
        float4 qa2 = recb[(r + 2) * 3], qb2 = recb[(r + 2) * 3 + 1], qc2 = recb[(r + 2) * 3 + 2];
        float4 qa3 = recb[(r + 3) * 3], qb3 = recb[(r + 3) * 3 + 1], qc3 = recb[(r + 3) * 3 + 2];
        int s0 = __float_as_int(qc0.z), s1 = __float_as_int(qc1.z);
        int s2 = __float_as_int(qc2.z), s3 = __float_as_int(qc3.z);
        if (comp) {
            uint2 v0 = *(const uint2*)(Bu + (size_t)s0 * TF + 4 * lane);
            uint2 v1 = *(const uint2*)(Bu + (size_t)s1 * TF + 4 * lane);
            uint2 v2 = *(const uint2*)(Bu + (size_t)s2 * TF + 4 * lane);
            uint2 v3 = *(const uint2*)(Bu + (size_t)s3 * TF + 4 * lane);
            edge(qa0, qb0, qc0, v0);
            edge(qa1, qb1, qc1, v1);
            edge(qa2, qb2, qc2, v2);
            edge(qa3, qb3, qc3, v3);
        }
    }
    if (sub == 0) {
        for (int rr = deg & ~3; rr < deg; rr++) {
            float4 qa = recb[rr * 3], qb = recb[rr * 3 + 1], qc = recb[rr * 3 + 2];
            int sn = __float_as_int(qc.z);
            if (comp) {
                uint2 bv = *(const uint2*)(Bu + (size_t)sn * TF + 4 * lane);
                edge(qa, qb, qc, bv);
            }
        }
    }
    // ---- merge sub-wave 1 partials into sub-wave 0 ----
    if (comp && sub == 1) {
        float* mb = mrg + (nd * 16) * 52 + lane;
        mb[0 * 52] = sx;  mb[1 * 52] = sy;  mb[2 * 52] = sz;  mb[3 * 52] = sw_;
        mb[4 * 52] = qx;  mb[5 * 52] = qy;  mb[6 * 52] = qz;  mb[7 * 52] = qw;
        mb[8 * 52] = mnx; mb[9 * 52] = mny; mb[10 * 52] = mnz; mb[11 * 52] = mnw;
        mb[12 * 52] = mxx; mb[13 * 52] = mxy; mb[14 * 52] = mxz; mb[15 * 52] = mxw;
    }
    __syncthreads();
    if (comp && sub == 0) {
        const float* mb = mrg + (nd * 16) * 52 + lane;
        sx += mb[0 * 52];  sy += mb[1 * 52];  sz += mb[2 * 52];  sw_ += mb[3 * 52];
        qx += mb[4 * 52];  qy += mb[5 * 52];  qz += mb[6 * 52];  qw += mb[7 * 52];
        mnx = fminf(mnx, mb[8 * 52]);  mny = fminf(mny, mb[9 * 52]);
        mnz = fminf(mnz, mb[10 * 52]); mnw = fminf(mnw, mb[11 * 52]);
        mxx = fmaxf(mxx, mb[12 * 52]); mxy = fmaxf(mxy, mb[13 * 52]);
        mxz = fmaxf(mxz, mb[14 * 52]); mxw = fmaxf(mxw, mb[15 * 52]);

        float d = (float)deg, c1 = fmaxf(d, 1.0f);
        float inv = 1.0f / c1;
        float mex = (d * a4.x + sx) * inv, mey = (d * a4.y + sy) * inv;
        float mez = (d * a4.z + sz) * inv, mew = (d * a4.w + sw_) * inv;
        float msx = (d * a4.x * a4.x + 2.0f * a4.x * sx + qx) * inv;
        float msy = (d * a4.y * a4.y + 2.0f * a4.y * sy + qy) * inv;
        float msz = (d * a4.z * a4.z + 2.0f * a4.z * sz + qz) * inv;
        float msw = (d * a4.w * a4.w + 2.0f * a4.w * sw_ + qw) * inv;
        float4 mean4 = make_float4(mex, mey, mez, mew);
        float4 sd4 = make_float4(sqrtf(fmaxf(msx - mex * mex, 0.0f) + EPSV),
                                 sqrtf(fmaxf(msy - mey * mey, 0.0f) + EPSV),
                                 sqrtf(fmaxf(msz - mez * mez, 0.0f) + EPSV),
                                 sqrtf(fmaxf(msw - mew * mew, 0.0f) + EPSV));
        bool has = deg > 0;
        float4 mnv4 = has ? make_float4(a4.x + mnx, a4.y + mny, a4.z + mnz, a4.w + mnw)
                          : make_float4(0, 0, 0, 0);
        float4 mxv4 = has ? make_float4(a4.x + mxx, a4.y + mxy, a4.z + mxz, a4.w + mxw)
                          : make_float4(0, 0, 0, 0);
        int j0 = 4 * lane;
        int t = j0 / H, f = j0 - t * H;
        float* sb = sst + nd * 800 + t * 160 + f;      // [mean(40)|mn(40)|mx(40)|std(40)] per t
        *(float4*)(sb)       = mean4;
        *(float4*)(sb + 40)  = mnv4;
        *(float4*)(sb + 80)  = mxv4;
        *(float4*)(sb + 120) = sd4;
    }
    __syncthreads();

    // ---- projection: threads 0..255 (op 0..127, half = fs range); bf16 Wp4 read once per block ----
    float p0 = 0, p1 = 0, p2 = 0, p3 = 0;
    int op = tid & 127, half = (tid >> 7) & 1;
    if (tid < 256) {
        int tt = op / 24; if (tt > 4) tt = 4;
        const uint16_t* wtp = (const uint16_t*)Wp4b + (size_t)(half * 20) * 512 + op * 4;
        const float* sb0 = sst + tt * 160 + half * 80;
        #pragma unroll 4
        for (int k = 0; k < 20; k++) {
            uint2 wb = *(const uint2*)(wtp + (size_t)k * 512);
            float wx = __uint_as_float(wb.x << 16);
            float wy = __uint_as_float(wb.x & 0xffff0000u);
            float wz = __uint_as_float(wb.y << 16);
            float ww = __uint_as_float(wb.y & 0xffff0000u);
            const float* sp = sb0 + k * 4;
            float4 v0 = *(const float4*)(sp);
            float4 v1 = *(const float4*)(sp + 800);
            float4 v2 = *(const float4*)(sp + 1600);
            float4 v3 = *(const float4*)(sp + 2400);
            p0 += v0.x * wx + v0.y * wy + v0.z * wz + v0.w * ww;
            p1 += v1.x * wx + v1.y * wy + v1.z * wz + v1.w * ww;
            p2 += v2.x * wx + v2.y * wy + v2.z * wz + v2.w * ww;
            p3 += v3.x * wx + v3.y * wy + v3.z * wz + v3.w * ww;
        }
    }
    __syncthreads();              // all sst reads complete before aliasing as spart
    if (tid < 256 && op < 120) {
        spart[(0 * 120 + op) * 2 + half] = p0;
        spart[(1 * 120 + op) * 2 + half] = p1;
        spart[(2 * 120 + op) * 2 + half] = p2;
        spart[(3 * 120 + op) * 2 + half] = p3;
    }
    __syncthreads();

    // ---- combine: cpre[nd][j] = post_b + ya + amp*yb + att*yc + h'@Wx  (stays in LDS) ----
    if (tid < 160) {
        int ndc = tid / H, j = tid - ndc * H;  // j = t*8+o
        int t = j >> 3, o = j & 7;
        int ng = n0 + ndc;
        float am = amp[ng], at = att[ng];
        const float* yr = spart + (ndc * 120 + t * 24) * 2;
        float pa = yr[o * 2]        + yr[o * 2 + 1];
        float pb = yr[(8 + o) * 2]  + yr[(8 + o) * 2 + 1];
        float pc = yr[(16 + o) * 2] + yr[(16 + o) * 2 + 1];
        float acc = pbL[j] + pa + am * pb + at * pc;
        const float* hr = shh + ndc * H;
        const float* wx = Wxd + (size_t)j * H;
        #pragma unroll
        for (int fq = 0; fq < 10; fq++) {
            float4 hv = *(const float4*)(hr + fq * 4);
            float4 wv = *(const float4*)(wx + fq * 4);
            acc += hv.x * wv.x + hv.y * wv.y + hv.z * wv.z + hv.w * wv.w;
        }
        scp[tid] = acc;
    }
    __syncthreads();

    // ---- lin: cbuf[n][j] = lin_b[j] + cpre[n] @ lin_w[:,j] ----
    if (tid < 160) {
        int ndc = tid / H, j = tid - ndc * H;
        const float* scr = scp + ndc * H;
        float lacc = lbL[j];
        #pragma unroll
        for (int k = 0; k < H; k++) lacc = fmaf(scr[k], lwL[k * H + j], lacc);
        cbuf[(size_t)(n0 + ndc) * H + j] = lacc;
        lred[tid] = lacc;
    }
    __syncthreads();

    // ---- BN partial sums -> compact superblock buffer [SUPB][80] via atomics ----
    if (tid < 80) {
        int c2 = tid / 40, j = tid - c2 * 40;
        float s = 0.0f;
        #pragma unroll
        for (int ndc = 0; ndc < 4; ndc++) {
            float v = lred[ndc * 40 + j];
            s += c2 ? v * v : v;
        }
        atomicAdd(&partials2[(size_t)(blockIdx.x >> 6) * 80 + tid], s);
    }
}

// ---------- final prep: reduce L1 partials + fused BN+residual in LDS, then P1/P2 (50 nodes/block) ----------
__global__ __launch_bounds__(256) void k_prep2(const float* __restrict__ h, const float* __restrict__ cbuf,
                                               const float* __restrict__ partials2,
                                               const float* __restrict__ bng, const float* __restrict__ bnb,
                                               const float* __restrict__ w1,
                                               float* __restrict__ P1, float* __restrict__ P2) {
    __shared__ float bns[80];
    __shared__ float sh[50 * H];             // 8 KB
    int tid = threadIdx.x;
    int n0 = blockIdx.x * 50;                // NN % 50 == 0
    if (tid < 80) {
        float s = 0.0f;
        for (int i = 0; i < SUPB; i++) s += partials2[i * 80 + tid];
        bns[tid] = s;
    }
    __syncthreads();
    float invN = 1.0f / (float)NN;
    for (int idx = tid; idx < 50 * H; idx += 256) {
        int j = idx % H;
        float mu = bns[j] * invN;
        float var = bns[40 + j] * invN - mu * mu;
        float inv = rsqrtf(var + EPSV);
        float cv = (cbuf[(size_t)n0 * H + idx] - mu) * inv * bng[j] + bnb[j];
        sh[idx] = (h[(size_t)n0 * H + idx] + fmaxf(cv, 0.0f)) * 0.5f;
    }
    __syncthreads();
    for (int idx = tid; idx < 50 * 50; idx += 256) {
        int nl = idx / 50, o = idx - nl * 50;
        const float* hr = sh + nl * H;
        float a1 = 0.0f, a2 = 0.0f;
        #pragma unroll
        for (int f = 0; f < H; f++) {
            float v = fmaxf(hr[f], 0.0f);
            a1 += v * w1[f * 50 + o];
            a2 += v * w1[(H + f) * 50 + o];
        }
        P1[(size_t)(n0 + nl) * PSTR + o] = a1;
        P2[(size_t)(n0 + nl) * PSTR + o] = a2;
    }
}

// ---------- final edge MLP: all weights via uniform scalar loads (no LDS) ----------
__global__ __launch_bounds__(256) void k_mlp(const float* __restrict__ ea_csr, const int* __restrict__ pdst,
                                             const float* __restrict__ P1, const float* __restrict__ P2,
                                             const float* __restrict__ W1e, const float* __restrict__ b1e,
                                             const float* __restrict__ w2, const float* __restrict__ b2,
                                             const float* __restrict__ w3, const float* __restrict__ b3,
                                             float* __restrict__ out) {
    int p = blockIdx.x * 256 + threadIdx.x;
    if (p >= NE) return;
    const float4* rec = (const float4*)ea_csr + (size_t)p * 3;
    float4 r0 = rec[0], r1 = rec[1], r2 = rec[2];
    int s = __float_as_int(r2.z), eid = __float_as_int(r2.w);
    int d = pdst[p];
    float ea[EFD] = {r0.x, r0.y, r0.z, r0.w, r1.x, r1.y, r1.z, r1.w, r2.x, r2.y};

    float z1[52];
    const float4* p1r = (const float4*)(P1 + (size_t)s * PSTR);
    const float4* p2r = (const float4*)(P2 + (size_t)d * PSTR);
    #pragma unroll
    for (int i = 0; i < 13; i++) {
        float4 a = p1r[i], b = p2r[i];
        z1[4 * i]     = a.x + b.x;
        z1[4 * i + 1] = a.y + b.y;
        z1[4 * i + 2] = a.z + b.z;
        z1[4 * i + 3] = a.w + b.w;
    }
    #pragma unroll
    for (int k = 0; k < 50; k++) z1[k] += b1e[k];              // uniform -> scalar
    #pragma unroll
    for (int m = 0; m < EFD; m++) {
        float v = ea[m];
        #pragma unroll
        for (int k = 0; k < 50; k++) z1[k] = fmaf(v, W1e[m * 50 + k], z1[k]);
    }
    float z2[25];
    #pragma unroll
    for (int o = 0; o < 25; o++) z2[o] = b2[o];
    #pragma unroll
    for (int k = 0; k < 50; k++) {
        float v = fmaxf(z1[k], 0.0f);
        #pragma unroll
        for (int o = 0; o < 25; o++) z2[o] = fmaf(v, w2[k * 25 + o], z2[o]);
    }
    float o0 = b3[0], o1 = b3[1];
    #pragma unroll
    for (int k = 0; k < 25; k++) {
        float v = fmaxf(z2[k], 0.0f);
        o0 = fmaf(v, w3[k * 2], o0);
        o1 = fmaf(v, w3[k * 2 + 1], o1);
    }
    *(float2*)(out + (size_t)eid * 2) = make_float2(o0, o1);
}

extern "C" void kernel_launch(void* const* d_in, const int* in_sizes, int n_in,
                              void* d_out, int out_size, void* d_ws, size_t ws_size,
                              hipStream_t stream) {
    const float* x         = (const float*)d_in[0];
    const float* edge_attr = (const float*)d_in[1];
    const int*   eidx      = (const int*)  d_in[2];
    const float* node_w    = (const float*)d_in[3];
    const float* node_b    = (const float*)d_in[4];
    const float* edge_w    = (const float*)d_in[5];
    const float* edge_b    = (const float*)d_in[6];
    const float* enc_w     = (const float*)d_in[7];
    const float* enc_b     = (const float*)d_in[8];
    const float* pre_w     = (const float*)d_in[9];
    const float* pre_b     = (const float*)d_in[10];
    const float* post_w    = (const float*)d_in[11];
    const float* post_b    = (const float*)d_in[12];
    const float* lin_w     = (const float*)d_in[13];
    const float* lin_b     = (const float*)d_in[14];
    const float* bn_g      = (const float*)d_in[15];
    const float* bn_b      = (const float*)d_in[16];
    const float* w1 = (const float*)d_in[17];
    const float* b1 = (const float*)d_in[18];
    const float* w2 = (const float*)d_in[19];
    const float* b2 = (const float*)d_in[20];
    const float* w3 = (const float*)d_in[21];
    const float* b3 = (const float*)d_in[22];
    const int* srcp = eidx;
    const int* dstp = eidx + NE;
    float* out = (float*)d_out;

    char* ws = (char*)d_ws;
    size_t off = 0;
    auto alloc = [&](size_t bytes) -> char* {
        char* p = ws + off;
        off += (bytes + 255) & ~(size_t)255;
        return p;
    };
    float* h      = (float*)alloc((size_t)NN * H * 4);
    float* Abuf   = (float*)alloc((size_t)NN * TF * 4);
    float* cbuf   = (float*)alloc((size_t)NN * H * 4);
    __hip_bfloat16* Bbf = (__hip_bfloat16*)alloc((size_t)NN * TF * 2 + 256);
    float* ea_csr = (float*)alloc((size_t)NE * REC * 4);
    int* pdst     = (int*)alloc((size_t)NE * 4);
    float* W3e    = (float*)alloc((size_t)LAYERS * EFD * TF * 4);
    float* dvecF  = (float*)alloc((size_t)LAYERS * TF * 4);
    __hip_bfloat16* Wcat = (__hip_bfloat16*)alloc((size_t)LAYERS * WCN * WCK * 2);
    __hip_bfloat16* Wp4b = (__hip_bfloat16*)alloc((size_t)LAYERS * 40 * 512 * 2);
    float* Wxd    = (float*)alloc((size_t)LAYERS * H * H * 4);
    float* P1     = (float*)alloc((size_t)NN * PSTR * 4);
    float* P2     = (float*)alloc((size_t)NN * PSTR * 4);
    float* W1e    = (float*)alloc((size_t)EFD * 50 * 4);
    float* b1e    = (float*)alloc((size_t)64 * 4);
    float* amp    = (float*)alloc((size_t)NN * 4);
    float* att    = (float*)alloc((size_t)NN * 4);
    int* offs     = (int*)alloc((size_t)(NN + 1) * 4);
    // ---- contiguous zero region: cnt, fill, partials2(2 layers) ----
    size_t zoff = off;
    int* cnt_i    = (int*)alloc((size_t)NN * 4);
    int* fill     = (int*)alloc((size_t)NN * 4);
    float* partials2 = (float*)alloc((size_t)LAYERS * SUPB * 80 * 4);
    size_t zsize = off - zoff;
    if (off > ws_size) return;

    hipMemsetAsync(cnt_i, 0, zsize, stream);

    int prep1_tot = EFD * TF + WCN * WCK + EFD * 50 + 40 * 512 + H * H;
    int prep1_grid = (prep1_tot + 255) / 256;
    int gdeg = (NE + 255) / 256;
    int gh0 = (NN * H + 255) / 256;
    k_front<<<2 * prep1_grid + gdeg + gh0, 256, 0, stream>>>(
        enc_w, enc_b, edge_w, edge_b, pre_w, pre_b, post_w, w1, b1,
        W3e, dvecF, Wcat, Wp4b, Wxd, W1e, b1e,
        dstp, cnt_i, x, node_w, node_b, h, prep1_grid, gdeg);

    k_scan<<<1, 1024, 0, stream>>>(cnt_i, offs, amp, att);

    int gab = (NN + 63) / 64;
    int gsc = (NE + 255) / 256;
    k_mid<<<gab + gsc, 256, 0, stream>>>(srcp, dstp, edge_attr, offs, fill, ea_csr, pdst,
                                         h, Wcat, Abuf, Bbf, gab);

    for (int layer = 0; layer < LAYERS; layer++) {
        if (layer > 0) {
            k_abm<<<gab, 256, 0, stream>>>(
                h, cbuf, partials2, bn_g, bn_b,
                Wcat + (size_t)WCN * WCK, Abuf, Bbf);
        }
        k_agg<<<NBLK, 512, 0, stream>>>(ea_csr, Bbf, Abuf,
                                        W3e + (size_t)layer * EFD * TF,
                                        dvecF + (size_t)layer * TF,
                                        cnt_i, offs, h,
                                        Wp4b + (size_t)layer * 40 * 512,
                                        Wxd + (size_t)layer * H * H,
                                        post_b + (size_t)layer * T * FO,
                                        amp, att,
                                        lin_w + (size_t)layer * H * H, lin_b + (size_t)layer * H,
                                        cbuf, partials2 + (size_t)layer * SUPB * 80);
    }
    k_prep2<<<NN / 50, 256, 0, stream>>>(h, cbuf, partials2 + (size_t)SUPB * 80,
                                         bn_g + H, bn_b + H, w1, P1, P2);
    k_mlp<<<(NE + 255) / 256, 256, 0, stream>>>(ea_csr, pdst, P1, P2, W1e, b1e, w2, b2, w3, b3, out);
}

// Round 16
// 479.992 us; speedup vs baseline: 1.5354x; 1.5354x over previous
//
#include <hip/hip_runtime.h>
#include <hip/hip_bf16.h>
#include <cstdint>
#include <cstddef>

#define NN 25000
#define NE 400000
#define NFD 30
#define EFD 10
#define H 40
#define T 5
#define FO 8
#define LAYERS 2
#define TF 200          // T*F
#define PSTR 52         // padded row stride for P1/P2
#define REC 12          // floats per CSR edge record [ea0..9, src, eid]
#define WCN 416         // Wcat rows: A j 0..199 | pad | B j 208..407 | pad
#define WCK 64          // Wcat K (40 real + 24 zero-pad)
#define SHP 72          // LDS bf16 row stride for h tile
#define NBLK (NN / 4)   // k_agg grid
#define SUPB ((NBLK + 63) / 64)   // 98 compact-partial superblocks
#define EPSV 1e-5f

typedef __attribute__((ext_vector_type(8))) short bf16x8;
typedef __attribute__((ext_vector_type(4))) float f32x4;

__device__ inline short bfbits(float v) {
    __hip_bfloat16 b = __float2bfloat16(v);
    return *(short*)&b;
}

// ---------- fused front: prep1(both layers) || degree histogram || h0 matmul ----------
__global__ __launch_bounds__(256) void k_front(const float* __restrict__ enc_w, const float* __restrict__ enc_b,
                                               const float* __restrict__ edge_w, const float* __restrict__ edge_b,
                                               const float* __restrict__ pre_w, const float* __restrict__ pre_b,
                                               const float* __restrict__ post_w,
                                               const float* __restrict__ w1, const float* __restrict__ b1,
                                               float* __restrict__ W3e, float* __restrict__ dvecF,
                                               __hip_bfloat16* __restrict__ Wcat,
                                               __hip_bfloat16* __restrict__ Wp4b, float* __restrict__ Wxd,
                                               float* __restrict__ W1e, float* __restrict__ b1e,
                                               const int* __restrict__ dst, int* __restrict__ cnt,
                                               const float* __restrict__ x, const float* __restrict__ node_w,
                                               const float* __restrict__ node_b, float* __restrict__ h,
                                               int grid1, int gdeg) {
    int blk = blockIdx.x;
    int tid = threadIdx.x;
    if (blk < 2 * grid1) {
        // ----- prep1, both layers -----
        int layer = (blk >= grid1) ? 1 : 0;
        int id = (blk - layer * grid1) * 256 + tid;
        W3e   += (size_t)layer * EFD * TF;
        dvecF += (size_t)layer * TF;
        Wcat  += (size_t)layer * WCN * WCK;
        Wp4b  += (size_t)layer * 40 * 512;
        Wxd   += (size_t)layer * H * H;
        const int B0 = EFD * TF;            // 2000
        const int B1 = B0 + WCN * WCK;      // 28624
        const int B2 = B1 + EFD * 50;       // 29124
        const int B3 = B2 + 40 * 512;       // 49604  (Wp4b[fs4][op 0..127][4], bf16)
        const int B4 = B3 + H * H;          // 51204  (Wxd: 40j x 40f)
        if (id < B0) {
            int m = id / TF, j = id - m * TF;
            int t = j / H, f = j - t * H;
            const float* ew = enc_w + (size_t)layer * H * H;
            const float* pw = pre_w + (size_t)(layer * T + t) * 120 * H;
            float acc = 0.0f;
            for (int k = 0; k < H; k++) {
                float wk = edge_w[m * H + k];
                float g = 0.0f;
                #pragma unroll
                for (int o = 0; o < H; o++) g += ew[k * H + o] * pw[(80 + o) * H + f];
                acc += wk * g;
            }
            W3e[m * TF + j] = acc;
            if (m == 0) {
                const float* eb = enc_b + (size_t)layer * H;
                float dacc = pre_b[(size_t)(layer * T + t) * H + f];
                for (int o = 0; o < H; o++) {
                    float ebe = eb[o];
                    #pragma unroll
                    for (int k = 0; k < H; k++) ebe += edge_b[k] * ew[k * H + o];
                    dacc += ebe * pw[(80 + o) * H + f];
                }
                dvecF[j] = dacc;
            }
        } else if (id < B1) {
            int id2 = id - B0;
            int j = id2 / WCK, k = id2 - j * WCK;
            float val = 0.0f;
            if (k < H) {
                if (j < TF) {                      // A weights: p1 part, pre_w[t][k][f]
                    int t = j / H, f = j - t * H;
                    val = pre_w[((size_t)(layer * T + t) * 120 + k) * H + f];
                } else if (j >= 208 && j < 208 + TF) {   // B weights: p2 part, pre_w[t][40+k][f]
                    int j2 = j - 208;
                    int t = j2 / H, f = j2 - t * H;
                    val = pre_w[((size_t)(layer * T + t) * 120 + H + k) * H + f];
                }
            }
            Wcat[id2] = __float2bfloat16(val);
        } else if (id < B2) {
            if (layer == 0) {
                int id2 = id - B1;
                int m = id2 / 50, o = id2 - m * 50;
                float acc = 0.0f;
                #pragma unroll
                for (int k = 0; k < H; k++) acc += edge_w[m * H + k] * w1[(80 + k) * 50 + o];
                W1e[m * 50 + o] = acc;
                if (m == 0) {
                    float bacc = b1[o];
                    #pragma unroll
                    for (int k = 0; k < H; k++) bacc += edge_b[k] * w1[(80 + k) * 50 + o];
                    b1e[o] = bacc;
                }
            }
        } else if (id < B3) {
            // Wp4b[fs4*512 + col*4 + c]; fs = fs4*4+c in [0,160); col = t*24+grp*8+o (<120)
            int i2 = id - B2;
            int fs4 = i2 >> 9;
            int rem = i2 & 511;
            int col = rem >> 2, c = rem & 3;
            int fs = fs4 * 4 + c;
            float v = 0.0f;
            if (col < 120) {
                int t = col / 24, r2 = col - t * 24;
                int grp = r2 >> 3, o = r2 & 7;
                v = post_w[((size_t)(layer * T + t) * 520 + 40 + grp * 160 + fs) * FO + o];
            }
            Wp4b[i2] = __float2bfloat16(v);
        } else if (id < B4) {
            // Wxd[j*40 + f] = post_w[t][f][o], j = t*8+o
            int i2 = id - B3;
            int j = i2 / H, f = i2 - j * H;
            int t = j >> 3, o = j & 7;
            Wxd[i2] = post_w[((size_t)(layer * T + t) * 520 + f) * FO + o];
        }
    } else if (blk < 2 * grid1 + gdeg) {
        // ----- degree histogram -----
        int e = (blk - 2 * grid1) * 256 + tid;
        if (e < NE) atomicAdd(&cnt[dst[e]], 1);
    } else {
        // ----- h0 = x @ node_w + node_b -----
        int id = (blk - 2 * grid1 - gdeg) * 256 + tid;
        if (id >= NN * H) return;
        int n = id / H, j = id - n * H;
        const float* xr = x + (size_t)n * NFD;
        float acc = node_b[j];
        #pragma unroll
        for (int m = 0; m < NFD; m++) acc += xr[m] * node_w[m * H + j];
        h[id] = acc;
    }
}

// ---------- exclusive scan of cnt -> offsets (shfl-based) + avglog + amp/att ----------
__global__ __launch_bounds__(1024) void k_scan(const int* __restrict__ cnt, int* __restrict__ offs,
                                               float* __restrict__ amp, float* __restrict__ att) {
    __shared__ int wsum[16];
    __shared__ float fsum[16];
    __shared__ float favg;
    int tid = threadIdx.x;
    int lane = tid & 63, wv = tid >> 6;
    // --- log-sum for avg (k_avglog folded in) ---
    {
        float s = 0.0f;
        for (int i = tid; i < NN; i += 1024) s += logf((float)cnt[i] + 1.0f);
        #pragma unroll
        for (int o = 32; o > 0; o >>= 1) s += __shfl_down(s, o);
        if (lane == 0) fsum[wv] = s;
        __syncthreads();
        if (tid == 0) {
            float a = 0.0f;
            #pragma unroll
            for (int i = 0; i < 16; i++) a += fsum[i];
            favg = a / (float)NN;
        }
        __syncthreads();
    }
    float avg = favg;
    int runbase = 0;
    for (int base = 0; base < NN; base += 4096) {
        int i0 = base + tid * 4;
        int4 v = make_int4(0, 0, 0, 0);
        if (i0 < NN) v = *(const int4*)(cnt + i0);   // NN % 4 == 0
        if (i0 < NN) {
            #pragma unroll
            for (int c = 0; c < 4; c++) {
                int cv = (&v.x)[c];
                float c1 = fmaxf((float)cv, 1.0f);
                float lg = logf(c1 + 1.0f);
                amp[i0 + c] = lg / avg;
                att[i0 + c] = avg / lg;
            }
        }
        int tsum = v.x + v.y + v.z + v.w;
        int x = tsum;
        #pragma unroll
        for (int o = 1; o < 64; o <<= 1) {
            int y = __shfl_up(x, o);
            if (lane >= o) x += y;
        }
        if (lane == 63) wsum[wv] = x;
        __syncthreads();
        if (wv == 0 && lane < 16) {
            int wsv = wsum[lane];
            #pragma unroll
            for (int o = 1; o < 16; o <<= 1) {
                int y = __shfl_up(wsv, o);
                if (lane >= o) wsv += y;
            }
            wsum[lane] = wsv;
        }
        __syncthreads();
        int wpref = (wv > 0) ? wsum[wv - 1] : 0;
        int excl = runbase + wpref + x - tsum;
        if (i0 < NN) {
            offs[i0]     = excl;
            offs[i0 + 1] = excl + v.x;
            offs[i0 + 2] = excl + v.x + v.y;
            offs[i0 + 3] = excl + v.x + v.y + v.z;
        }
        runbase += wsum[15];
        __syncthreads();
    }
    if (tid == 0) offs[NN] = runbase;
}

// ---------- fused mid: edge scatter || MFMA A/B for layer 0 (independent workloads) ----------
__global__ __launch_bounds__(256) void k_mid(const int* __restrict__ src, const int* __restrict__ dst,
                                             const float* __restrict__ edge_attr,
                                             const int* __restrict__ offs, int* __restrict__ fill,
                                             float* __restrict__ ea_csr, int* __restrict__ pdst,
                                             const float* __restrict__ h,
                                             const __hip_bfloat16* __restrict__ Wcat,
                                             float* __restrict__ A, __hip_bfloat16* __restrict__ Bbf,
                                             int gab) {
    __shared__ short sh[64 * SHP];           // bf16 bits, zero-padded K (abm path only)
    int blk = blockIdx.x;
    int tid = threadIdx.x;
    if (blk < gab) {
        // ----- abm L0: [64 nodes x 40] @ Wcat -> A fp32, Bbf bf16 -----
        int n0 = blk * 64;
        int nodes = NN - n0; if (nodes > 64) nodes = 64;
        for (int i = tid; i < 64 * SHP; i += 256) sh[i] = 0;
        __syncthreads();
        for (int i = tid; i < nodes * H; i += 256) {
            int f = i % H;
            sh[(i / H) * SHP + f] = bfbits(h[(size_t)n0 * H + i]);
        }
        __syncthreads();

        int wv = tid >> 6, lane = tid & 63;
        int q = lane >> 4, c16 = lane & 15;
        const short* arow = sh + (wv * 16 + c16) * SHP + q * 8;
        bf16x8 a0 = *(const bf16x8*)(arow);       // chunk 0: K 0..31
        bf16x8 a1 = *(const bf16x8*)(arow + 32);  // chunk 1: K 32..63 (zeros beyond 40)
        int gm = n0 + wv * 16 + q * 4;            // D rows: gm..gm+3

        for (int jt = 0; jt < 26; jt++) {
            int col = jt * 16 + c16;
            const short* wrow = (const short*)Wcat + (size_t)col * WCK + q * 8;
            bf16x8 b0 = *(const bf16x8*)(wrow);
            bf16x8 b1 = *(const bf16x8*)(wrow + 32);
            f32x4 acc = {0.0f, 0.0f, 0.0f, 0.0f};
            acc = __builtin_amdgcn_mfma_f32_16x16x32_bf16(a0, b0, acc, 0, 0, 0);
            acc = __builtin_amdgcn_mfma_f32_16x16x32_bf16(a1, b1, acc, 0, 0, 0);
            if (col < TF) {
                #pragma unroll
                for (int r = 0; r < 4; r++) {
                    int row = gm + r;
                    if (row < NN) A[(size_t)row * TF + col] = acc[r];
                }
            } else if (col >= 208) {
                int c2 = col - 208;
                if (c2 < TF) {
                    #pragma unroll
                    for (int r = 0; r < 4; r++) {
                        int row = gm + r;
                        if (row < NN) Bbf[(size_t)row * TF + c2] = __float2bfloat16(acc[r]);
                    }
                }
            }
        }
    } else {
        // ----- scatter edges into CSR records [ea0..9, src, eid] + pdst -----
        int e = (blk - gab) * 256 + tid;
        if (e >= NE) return;
        int d = dst[e];
        int p = offs[d] + atomicAdd(&fill[d], 1);
        const float2* ear = (const float2*)(edge_attr + (size_t)e * EFD);
        float2 v0 = ear[0], v1 = ear[1], v2 = ear[2], v3 = ear[3], v4 = ear[4];
        float4* o = (float4*)(ea_csr + (size_t)p * REC);
        o[0] = make_float4(v0.x, v0.y, v1.x, v1.y);
        o[1] = make_float4(v2.x, v2.y, v3.x, v3.y);
        o[2] = make_float4(v4.x, v4.y, __int_as_float(src[e]), __int_as_float(e));
        pdst[p] = d;
    }
}

// ---------- MFMA A/B with fused BN+residual (layer 1); reduces compact L0 partials in prologue ----------
__global__ __launch_bounds__(256) void k_abm(float* h, const float* __restrict__ cbuf,
                                             const float* __restrict__ partials2,
                                             const float* __restrict__ bng, const float* __restrict__ bnb,
                                             const __hip_bfloat16* __restrict__ Wcat,
                                             float* __restrict__ A, __hip_bfloat16* __restrict__ Bbf) {
    __shared__ short sh[64 * SHP];           // bf16 bits, zero-padded K
    __shared__ float bns[80];                // [sum(40) | sumsq(40)]
    int tid = threadIdx.x;
    int n0 = blockIdx.x * 64;
    int nodes = NN - n0; if (nodes > 64) nodes = 64;
    if (tid < 80) {
        float s = 0.0f;
        for (int i = 0; i < SUPB; i++) s += partials2[i * 80 + tid];
        bns[tid] = s;
    }
    for (int i = tid; i < 64 * SHP; i += 256) sh[i] = 0;
    __syncthreads();
    float invN = 1.0f / (float)NN;
    for (int i = tid; i < nodes * H; i += 256) {
        int f = i % H;
        float hv = h[(size_t)n0 * H + i];
        float mu = bns[f] * invN;
        float var = bns[40 + f] * invN - mu * mu;
        float c = (cbuf[(size_t)n0 * H + i] - mu) * rsqrtf(var + EPSV) * bng[f] + bnb[f];
        float hn = (hv + fmaxf(c, 0.0f)) * 0.5f;
        h[(size_t)n0 * H + i] = hn;          // materialize h' for k_agg combine
        sh[(i / H) * SHP + f] = bfbits(hn);
    }
    __syncthreads();

    int wv = tid >> 6, lane = tid & 63;
    int q = lane >> 4, c16 = lane & 15;
    const short* arow = sh + (wv * 16 + c16) * SHP + q * 8;
    bf16x8 a0 = *(const bf16x8*)(arow);       // chunk 0: K 0..31
    bf16x8 a1 = *(const bf16x8*)(arow + 32);  // chunk 1: K 32..63 (zeros beyond 40)
    int gm = n0 + wv * 16 + q * 4;            // D rows: gm..gm+3

    for (int jt = 0; jt < 26; jt++) {
        int col = jt * 16 + c16;
        const short* wrow = (const short*)Wcat + (size_t)col * WCK + q * 8;
        bf16x8 b0 = *(const bf16x8*)(wrow);
        bf16x8 b1 = *(const bf16x8*)(wrow + 32);
        f32x4 acc = {0.0f, 0.0f, 0.0f, 0.0f};
        acc = __builtin_amdgcn_mfma_f32_16x16x32_bf16(a0, b0, acc, 0, 0, 0);
        acc = __builtin_amdgcn_mfma_f32_16x16x32_bf16(a1, b1, acc, 0, 0, 0);
        if (col < TF) {                       // A region
            #pragma unroll
            for (int r = 0; r < 4; r++) {
                int row = gm + r;
                if (row < NN) A[(size_t)row * TF + col] = acc[r];
            }
        } else if (col >= 208) {
            int c2 = col - 208;
            if (c2 < TF) {                    // B region
                #pragma unroll
                for (int r = 0; r < 4; r++) {
                    int row = gm + r;
                    if (row < NN) Bbf[(size_t)row * TF + c2] = __float2bfloat16(acc[r]);
                }
            }
        }
    }
}

// ---------- aggregation + post-projection + lin + compact BN-partials, all fused ----------
__global__ __launch_bounds__(256) void k_agg(const float* __restrict__ ea_csr,
                                             const __hip_bfloat16* __restrict__ Bbf,
                                             const float* __restrict__ A, const float* __restrict__ w3e,
                                             const float* __restrict__ dvecF, const int* __restrict__ cnt,
                                             const int* __restrict__ offs,
                                             const float* __restrict__ h,
                                             const __hip_bfloat16* __restrict__ Wp4b, const float* __restrict__ Wxd,
                                             const float* __restrict__ pbL,
                                             const float* __restrict__ amp, const float* __restrict__ att,
                                             const float* __restrict__ lwL, const float* __restrict__ lbL,
                                             float* __restrict__ cbuf, float* __restrict__ partials2) {
    __shared__ float sst[4 * 800];           // per-node stats node-major; aliased after proj:
    __shared__ float shh[4 * H];             //   spart [0,960) | scp [1024,1184) | lred [1280,1440)
    float* spart = sst;
    float* scp   = sst + 1024;
    float* lred  = sst + 1280;
    int tid = threadIdx.x;
    int lane = tid & 63;
    int wv = tid >> 6;
    int n0 = blockIdx.x * 4;                 // NN % 4 == 0
    // SGPR node index -> scalar (SMEM) loads for deg/start/records (r4 post-mortem: critical)
    int n = __builtin_amdgcn_readfirstlane(n0 + wv);
    if (tid < 4 * H) shh[tid] = h[(size_t)n0 * H + tid];
    int deg = cnt[n];
    int start = offs[n];
    bool comp = lane < TF / 4; // lanes 0..49
    float4 w3q[EFD];
    float4 dj4 = make_float4(0, 0, 0, 0), a4 = make_float4(0, 0, 0, 0);
    if (comp) {
        #pragma unroll
        for (int m = 0; m < EFD; m++) w3q[m] = *(const float4*)(w3e + m * TF + 4 * lane);
        dj4 = *(const float4*)(dvecF + 4 * lane);
        a4  = *(const float4*)(A + (size_t)n * TF + 4 * lane);
    }
    float sx = 0, sy = 0, sz = 0, sw_ = 0;
    float qx = 0, qy = 0, qz = 0, qw = 0;
    float mnx = 3.4e38f, mny = 3.4e38f, mnz = 3.4e38f, mnw = 3.4e38f;
    float mxx = -3.4e38f, mxy = -3.4e38f, mxz = -3.4e38f, mxw = -3.4e38f;
    const float4* recb = (const float4*)ea_csr + (size_t)start * 3;
    const uint16_t* Bu = (const uint16_t*)Bbf;

    auto edge = [&](float4 qa, float4 qb, float4 qc, uint2 bv) {
        float b0 = __uint_as_float(bv.x << 16);
        float b1 = __uint_as_float(bv.x & 0xffff0000u);
        float b2 = __uint_as_float(bv.y << 16);
        float b3 = __uint_as_float(bv.y & 0xffff0000u);
        float eav[EFD] = {qa.x, qa.y, qa.z, qa.w, qb.x, qb.y, qb.z, qb.w, qc.x, qc.y};
        float cx = dj4.x, cy = dj4.y, cz = dj4.z, cw = dj4.w;
        #pragma unroll
        for (int m = 0; m < EFD; m++) {
            cx = fmaf(eav[m], w3q[m].x, cx);
            cy = fmaf(eav[m], w3q[m].y, cy);
            cz = fmaf(eav[m], w3q[m].z, cz);
            cw = fmaf(eav[m], w3q[m].w, cw);
        }
        float ux = b0 + cx, uy = b1 + cy, uz = b2 + cz, uw = b3 + cw;
        sx += ux; qx = fmaf(ux, ux, qx); mnx = fminf(mnx, ux); mxx = fmaxf(mxx, ux);
        sy += uy; qy = fmaf(uy, uy, qy); mny = fminf(mny, uy); mxy = fmaxf(mxy, uy);
        sz += uz; qz = fmaf(uz, uz, qz); mnz = fminf(mnz, uz); mxz = fmaxf(mxz, uz);
        sw_ += uw; qw = fmaf(uw, uw, qw); mnw = fminf(mnw, uw); mxw = fmaxf(mxw, uw);
    };

    int r = 0;
    for (; r + 4 <= deg; r += 4) {
        float4 qa0 = recb[(r + 0) * 3], qb0 = recb[(r + 0) * 3 + 1], qc0 = recb[(r + 0) * 3 + 2];
        float4 qa1 = recb[(r + 1) * 3], qb1 = recb[(r + 1) * 3 + 1], qc1 = recb[(r + 1) * 3 + 2];
        float4 qa2 = recb[(r + 2) * 3], qb2 = recb[(r + 2) * 3 + 1], qc2 = recb[(r + 2) * 3 + 2];
        float4 qa3 = recb[(r + 3) * 3], qb3 = recb[(r + 3) * 3 + 1], qc3 = recb[(r + 3) * 3 + 2];
        int s0 = __float_as_int(qc0.z), s1 = __float_as_int(qc1.z);
        int s2 = __float_as_int(qc2.z), s3 = __float_as_int(qc3.z);
        if (comp) {
            uint2 v0 = *(const uint2*)(Bu + (size_t)s0 * TF + 4 * lane);
            uint2 v1 = *(const uint2*)(Bu + (size_t)s1 * TF + 4 * lane);
            uint2 v2 = *(const uint2*)(Bu + (size_t)s2 * TF + 4 * lane);
            uint2 v3 = *(const uint2*)(Bu + (size_t)s3 * TF + 4 * lane);
            edge(qa0, qb0, qc0, v0);
            edge(qa1, qb1, qc1, v1);
            edge(qa2, qb2, qc2, v2);
            edge(qa3, qb3, qc3, v3);
        }
    }
    for (; r < deg; r++) {
        float4 qa = recb[r * 3], qb = recb[r * 3 + 1], qc = recb[r * 3 + 2];
        int sn = __float_as_int(qc.z);
        if (comp) {
            uint2 bv = *(const uint2*)(Bu + (size_t)sn * TF + 4 * lane);
            edge(qa, qb, qc, bv);
        }
    }
    if (comp) {
        float d = (float)deg, c1 = fmaxf(d, 1.0f);
        float inv = 1.0f / c1;
        float mex = (d * a4.x + sx) * inv, mey = (d * a4.y + sy) * inv;
        float mez = (d * a4.z + sz) * inv, mew = (d * a4.w + sw_) * inv;
        float msx = (d * a4.x * a4.x + 2.0f * a4.x * sx + qx) * inv;
        float msy = (d * a4.y * a4.y + 2.0f * a4.y * sy + qy) * inv;
        float msz = (d * a4.z * a4.z + 2.0f * a4.z * sz + qz) * inv;
        float msw = (d * a4.w * a4.w + 2.0f * a4.w * sw_ + qw) * inv;
        float4 mean4 = make_float4(mex, mey, mez, mew);
        float4 sd4 = make_float4(sqrtf(fmaxf(msx - mex * mex, 0.0f) + EPSV),
                                 sqrtf(fmaxf(msy - mey * mey, 0.0f) + EPSV),
                                 sqrtf(fmaxf(msz - mez * mez, 0.0f) + EPSV),
                                 sqrtf(fmaxf(msw - mew * mew, 0.0f) + EPSV));
        bool has = deg > 0;
        float4 mnv4 = has ? make_float4(a4.x + mnx, a4.y + mny, a4.z + mnz, a4.w + mnw)
                          : make_float4(0, 0, 0, 0);
        float4 mxv4 = has ? make_float4(a4.x + mxx, a4.y + mxy, a4.z + mxz, a4.w + mxw)
                          : make_float4(0, 0, 0, 0);
        int j0 = 4 * lane;
        int t = j0 / H, f = j0 - t * H;
        float* sb = sst + wv * 800 + t * 160 + f;      // [mean(40)|mn(40)|mx(40)|std(40)] per t
        *(float4*)(sb)       = mean4;
        *(float4*)(sb + 40)  = mnv4;
        *(float4*)(sb + 80)  = mxv4;
        *(float4*)(sb + 120) = sd4;
    }
    __syncthreads();

    // ---- projection: thread (op 0..127, half = fs range); bf16 Wp4 read once per block ----
    {
        int op = tid & 127, half = tid >> 7;
        int tt = op / 24; if (tt > 4) tt = 4;
        const uint16_t* wtp = (const uint16_t*)Wp4b + (size_t)(half * 20) * 512 + op * 4;
        const float* sb0 = sst + tt * 160 + half * 80;
        float p0 = 0, p1 = 0, p2 = 0, p3 = 0;
        #pragma unroll 4
        for (int k = 0; k < 20; k++) {
            uint2 wb = *(const uint2*)(wtp + (size_t)k * 512);
            float wx = __uint_as_float(wb.x << 16);
            float wy = __uint_as_float(wb.x & 0xffff0000u);
            float wz = __uint_as_float(wb.y << 16);
            float ww = __uint_as_float(wb.y & 0xffff0000u);
            const float* sp = sb0 + k * 4;
            float4 v0 = *(const float4*)(sp);
            float4 v1 = *(const float4*)(sp + 800);
            float4 v2 = *(const float4*)(sp + 1600);
            float4 v3 = *(const float4*)(sp + 2400);
            p0 += v0.x * wx + v0.y * wy + v0.z * wz + v0.w * ww;
            p1 += v1.x * wx + v1.y * wy + v1.z * wz + v1.w * ww;
            p2 += v2.x * wx + v2.y * wy + v2.z * wz + v2.w * ww;
            p3 += v3.x * wx + v3.y * wy + v3.z * wz + v3.w * ww;
        }
        __syncthreads();          // all sst reads complete before aliasing as spart
        if (op < 120) {
            spart[(0 * 120 + op) * 2 + half] = p0;
            spart[(1 * 120 + op) * 2 + half] = p1;
            spart[(2 * 120 + op) * 2 + half] = p2;
            spart[(3 * 120 + op) * 2 + half] = p3;
        }
    }
    __syncthreads();

    // ---- combine: cpre[nd][j] = post_b + ya + amp*yb + att*yc + h'@Wx  (stays in LDS) ----
    if (tid < 160) {
        int nd = tid / H, j = tid - nd * H;  // j = t*8+o
        int t = j >> 3, o = j & 7;
        int ng = n0 + nd;
        float am = amp[ng], at = att[ng];
        const float* yr = spart + (nd * 120 + t * 24) * 2;
        float pa = yr[o * 2]        + yr[o * 2 + 1];
        float pb = yr[(8 + o) * 2]  + yr[(8 + o) * 2 + 1];
        float pc = yr[(16 + o) * 2] + yr[(16 + o) * 2 + 1];
        float acc = pbL[j] + pa + am * pb + at * pc;
        const float* hr = shh + nd * H;
        const float* wx = Wxd + (size_t)j * H;
        #pragma unroll
        for (int fq = 0; fq < 10; fq++) {
            float4 hv = *(const float4*)(hr + fq * 4);
            float4 wv = *(const float4*)(wx + fq * 4);
            acc += hv.x * wv.x + hv.y * wv.y + hv.z * wv.z + hv.w * wv.w;
        }
        scp[tid] = acc;
    }
    __syncthreads();

    // ---- lin: cbuf[n][j] = lin_b[j] + cpre[n] @ lin_w[:,j] ----
    if (tid < 160) {
        int nd = tid / H, j = tid - nd * H;
        const float* scr = scp + nd * H;
        float lacc = lbL[j];
        #pragma unroll
        for (int k = 0; k < H; k++) lacc = fmaf(scr[k], lwL[k * H + j], lacc);
        cbuf[(size_t)(n0 + nd) * H + j] = lacc;
        lred[tid] = lacc;
    }
    __syncthreads();

    // ---- BN partial sums -> compact superblock buffer [SUPB][80] via atomics ----
    if (tid < 80) {
        int c2 = tid / 40, j = tid - c2 * 40;
        float s = 0.0f;
        #pragma unroll
        for (int nd = 0; nd < 4; nd++) {
            float v = lred[nd * 40 + j];
            s += c2 ? v * v : v;
        }
        atomicAdd(&partials2[(size_t)(blockIdx.x >> 6) * 80 + tid], s);
    }
}

// ---------- final prep: reduce L1 partials + fused BN+residual in LDS, then P1/P2 (50 nodes/block) ----------
__global__ __launch_bounds__(256) void k_prep2(const float* __restrict__ h, const float* __restrict__ cbuf,
                                               const float* __restrict__ partials2,
                                               const float* __restrict__ bng, const float* __restrict__ bnb,
                                               const float* __restrict__ w1,
                                               float* __restrict__ P1, float* __restrict__ P2) {
    __shared__ float bns[80];
    __shared__ float sh[50 * H];             // 8 KB
    int tid = threadIdx.x;
    int n0 = blockIdx.x * 50;                // NN % 50 == 0
    if (tid < 80) {
        float s = 0.0f;
        for (int i = 0; i < SUPB; i++) s += partials2[i * 80 + tid];
        bns[tid] = s;
    }
    __syncthreads();
    float invN = 1.0f / (float)NN;
    for (int idx = tid; idx < 50 * H; idx += 256) {
        int j = idx % H;
        float mu = bns[j] * invN;
        float var = bns[40 + j] * invN - mu * mu;
        float inv = rsqrtf(var + EPSV);
        float cv = (cbuf[(size_t)n0 * H + idx] - mu) * inv * bng[j] + bnb[j];
        sh[idx] = (h[(size_t)n0 * H + idx] + fmaxf(cv, 0.0f)) * 0.5f;
    }
    __syncthreads();
    for (int idx = tid; idx < 50 * 50; idx += 256) {
        int nl = idx / 50, o = idx - nl * 50;
        const float* hr = sh + nl * H;
        float a1 = 0.0f, a2 = 0.0f;
        #pragma unroll
        for (int f = 0; f < H; f++) {
            float v = fmaxf(hr[f], 0.0f);
            a1 += v * w1[f * 50 + o];
            a2 += v * w1[(H + f) * 50 + o];
        }
        P1[(size_t)(n0 + nl) * PSTR + o] = a1;
        P2[(size_t)(n0 + nl) * PSTR + o] = a2;
    }
}

// ---------- final edge MLP: all weights via uniform scalar loads (no LDS) ----------
__global__ __launch_bounds__(256) void k_mlp(const float* __restrict__ ea_csr, const int* __restrict__ pdst,
                                             const float* __restrict__ P1, const float* __restrict__ P2,
                                             const float* __restrict__ W1e, const float* __restrict__ b1e,
                                             const float* __restrict__ w2, const float* __restrict__ b2,
                                             const float* __restrict__ w3, const float* __restrict__ b3,
                                             float* __restrict__ out) {
    int p = blockIdx.x * 256 + threadIdx.x;
    if (p >= NE) return;
    const float4* rec = (const float4*)ea_csr + (size_t)p * 3;
    float4 r0 = rec[0], r1 = rec[1], r2 = rec[2];
    int s = __float_as_int(r2.z), eid = __float_as_int(r2.w);
    int d = pdst[p];
    float ea[EFD] = {r0.x, r0.y, r0.z, r0.w, r1.x, r1.y, r1.z, r1.w, r2.x, r2.y};

    float z1[52];
    const float4* p1r = (const float4*)(P1 + (size_t)s * PSTR);
    const float4* p2r = (const float4*)(P2 + (size_t)d * PSTR);
    #pragma unroll
    for (int i = 0; i < 13; i++) {
        float4 a = p1r[i], b = p2r[i];
        z1[4 * i]     = a.x + b.x;
        z1[4 * i + 1] = a.y + b.y;
        z1[4 * i + 2] = a.z + b.z;
        z1[4 * i + 3] = a.w + b.w;
    }
    #pragma unroll
    for (int k = 0; k < 50; k++) z1[k] += b1e[k];              // uniform -> scalar
    #pragma unroll
    for (int m = 0; m < EFD; m++) {
        float v = ea[m];
        #pragma unroll
        for (int k = 0; k < 50; k++) z1[k] = fmaf(v, W1e[m * 50 + k], z1[k]);
    }
    float z2[25];
    #pragma unroll
    for (int o = 0; o < 25; o++) z2[o] = b2[o];
    #pragma unroll
    for (int k = 0; k < 50; k++) {
        float v = fmaxf(z1[k], 0.0f);
        #pragma unroll
        for (int o = 0; o < 25; o++) z2[o] = fmaf(v, w2[k * 25 + o], z2[o]);
    }
    float o0 = b3[0], o1 = b3[1];
    #pragma unroll
    for (int k = 0; k < 25; k++) {
        float v = fmaxf(z2[k], 0.0f);
        o0 = fmaf(v, w3[k * 2], o0);
        o1 = fmaf(v, w3[k * 2 + 1], o1);
    }
    *(float2*)(out + (size_t)eid * 2) = make_float2(o0, o1);
}

extern "C" void kernel_launch(void* const* d_in, const int* in_sizes, int n_in,
                              void* d_out, int out_size, void* d_ws, size_t ws_size,
                              hipStream_t stream) {
    const float* x         = (const float*)d_in[0];
    const float* edge_attr = (const float*)d_in[1];
    const int*   eidx      = (const int*)  d_in[2];
    const float* node_w    = (const float*)d_in[3];
    const float* node_b    = (const float*)d_in[4];
    const float* edge_w    = (const float*)d_in[5];
    const float* edge_b    = (const float*)d_in[6];
    const float* enc_w     = (const float*)d_in[7];
    const float* enc_b     = (const float*)d_in[8];
    const float* pre_w     = (const float*)d_in[9];
    const float* pre_b     = (const float*)d_in[10];
    const float* post_w    = (const float*)d_in[11];
    const float* post_b    = (const float*)d_in[12];
    const float* lin_w     = (const float*)d_in[13];
    const float* lin_b     = (const float*)d_in[14];
    const float* bn_g      = (const float*)d_in[15];
    const float* bn_b      = (const float*)d_in[16];
    const float* w1 = (const float*)d_in[17];
    const float* b1 = (const float*)d_in[18];
    const float* w2 = (const float*)d_in[19];
    const float* b2 = (const float*)d_in[20];
    const float* w3 = (const float*)d_in[21];
    const float* b3 = (const float*)d_in[22];
    const int* srcp = eidx;
    const int* dstp = eidx + NE;
    float* out = (float*)d_out;

    char* ws = (char*)d_ws;
    size_t off = 0;
    auto alloc = [&](size_t bytes) -> char* {
        char* p = ws + off;
        off += (bytes + 255) & ~(size_t)255;
        return p;
    };
    float* h      = (float*)alloc((size_t)NN * H * 4);
    float* Abuf   = (float*)alloc((size_t)NN * TF * 4);
    float* cbuf   = (float*)alloc((size_t)NN * H * 4);
    __hip_bfloat16* Bbf = (__hip_bfloat16*)alloc((size_t)NN * TF * 2 + 256);
    float* ea_csr = (float*)alloc((size_t)NE * REC * 4);
    int* pdst     = (int*)alloc((size_t)NE * 4);
    float* W3e    = (float*)alloc((size_t)LAYERS * EFD * TF * 4);
    float* dvecF  = (float*)alloc((size_t)LAYERS * TF * 4);
    __hip_bfloat16* Wcat = (__hip_bfloat16*)alloc((size_t)LAYERS * WCN * WCK * 2);
    __hip_bfloat16* Wp4b = (__hip_bfloat16*)alloc((size_t)LAYERS * 40 * 512 * 2);
    float* Wxd    = (float*)alloc((size_t)LAYERS * H * H * 4);
    float* P1     = (float*)alloc((size_t)NN * PSTR * 4);
    float* P2     = (float*)alloc((size_t)NN * PSTR * 4);
    float* W1e    = (float*)alloc((size_t)EFD * 50 * 4);
    float* b1e    = (float*)alloc((size_t)64 * 4);
    float* amp    = (float*)alloc((size_t)NN * 4);
    float* att    = (float*)alloc((size_t)NN * 4);
    int* offs     = (int*)alloc((size_t)(NN + 1) * 4);
    // ---- contiguous zero region: cnt, fill, partials2(2 layers) ----
    size_t zoff = off;
    int* cnt_i    = (int*)alloc((size_t)NN * 4);
    int* fill     = (int*)alloc((size_t)NN * 4);
    float* partials2 = (float*)alloc((size_t)LAYERS * SUPB * 80 * 4);
    size_t zsize = off - zoff;
    if (off > ws_size) return;

    hipMemsetAsync(cnt_i, 0, zsize, stream);

    int prep1_tot = EFD * TF + WCN * WCK + EFD * 50 + 40 * 512 + H * H;
    int prep1_grid = (prep1_tot + 255) / 256;
    int gdeg = (NE + 255) / 256;
    int gh0 = (NN * H + 255) / 256;
    k_front<<<2 * prep1_grid + gdeg + gh0, 256, 0, stream>>>(
        enc_w, enc_b, edge_w, edge_b, pre_w, pre_b, post_w, w1, b1,
        W3e, dvecF, Wcat, Wp4b, Wxd, W1e, b1e,
        dstp, cnt_i, x, node_w, node_b, h, prep1_grid, gdeg);

    k_scan<<<1, 1024, 0, stream>>>(cnt_i, offs, amp, att);

    int gab = (NN + 63) / 64;
    int gsc = (NE + 255) / 256;
    k_mid<<<gab + gsc, 256, 0, stream>>>(srcp, dstp, edge_attr, offs, fill, ea_csr, pdst,
                                         h, Wcat, Abuf, Bbf, gab);

    for (int layer = 0; layer < LAYERS; layer++) {
        if (layer > 0) {
            k_abm<<<gab, 256, 0, stream>>>(
                h, cbuf, partials2, bn_g, bn_b,
                Wcat + (size_t)WCN * WCK, Abuf, Bbf);
        }
        k_agg<<<NBLK, 256, 0, stream>>>(ea_csr, Bbf, Abuf,
                                        W3e + (size_t)layer * EFD * TF,
                                        dvecF + (size_t)layer * TF,
                                        cnt_i, offs, h,
                                        Wp4b + (size_t)layer * 40 * 512,
                                        Wxd + (size_t)layer * H * H,
                                        post_b + (size_t)layer * T * FO,
                                        amp, att,
                                        lin_w + (size_t)layer * H * H, lin_b + (size_t)layer * H,
                                        cbuf, partials2 + (size_t)layer * SUPB * 80);
    }
    k_prep2<<<NN / 50, 256, 0, stream>>>(h, cbuf, partials2 + (size_t)SUPB * 80,
                                         bn_g + H, bn_b + H, w1, P1, P2);
    k_mlp<<<(NE + 255) / 256, 256, 0, stream>>>(ea_csr, pdst, P1, P2, W1e, b1e, w2, b2, w3, b3, out);
}